// Round 13
// baseline (948.431 us; speedup 1.0000x reference)
//
#include <hip/hip_runtime.h>
#include <hip/hip_bf16.h>
#include <math.h>

#define N_NODES 100000
#define N_EDGES 1000000
#define HALF_E  500000
#define H       128
#define NG      256
#define RELROWS 201
#define SCAN_NB 98   // 98 * 1024 >= 100000
#define XPITCH  136  // 128 + 8 bf16 pad
#define MMB     64   // rows per combine block

typedef __attribute__((ext_vector_type(8))) short bf16x8;
typedef __attribute__((ext_vector_type(4))) float f32x4;
typedef __attribute__((ext_vector_type(2))) float f32x2;

// ---- bf16 helpers (RNE) ----
__device__ __forceinline__ float bflo(unsigned p) { return __uint_as_float(p << 16); }
__device__ __forceinline__ float bfhi(unsigned p) { return __uint_as_float(p & 0xffff0000u); }
__device__ __forceinline__ unsigned packbf2(float a, float b) {
    unsigned ua = __float_as_uint(a), ub = __float_as_uint(b);
    ua = (ua + 0x7fffu + ((ua >> 16) & 1u)) >> 16;
    ub = (ub + 0x7fffu + ((ub >> 16) & 1u)) >> 16;
    return ua | (ub << 16);
}

// ---- fp8 e4m3 (OCP) helpers ----
__device__ __forceinline__ float fp8_to_f32(unsigned v) {
    unsigned s = (v & 0x80u) << 24;
    float m = __uint_as_float((v & 0x7fu) << 20) * 0x1p+120f;
    return __uint_as_float(__float_as_uint(m) | s);
}
#if __has_builtin(__builtin_amdgcn_cvt_pk_f32_fp8)
__device__ __forceinline__ f32x2 f8pair(unsigned short p) {
    return __builtin_amdgcn_cvt_pk_f32_fp8((int)(unsigned)p, false);
}
#else
__device__ __forceinline__ f32x2 f8pair(unsigned short p) {
    f32x2 r; r.x = fp8_to_f32(p & 0xffu); r.y = fp8_to_f32((p >> 8) & 0xffu); return r;
}
#endif
#if __has_builtin(__builtin_amdgcn_cvt_pk_fp8_f32)
__device__ __forceinline__ unsigned short packfp8_2(float a, float b) {
    int v = __builtin_amdgcn_cvt_pk_fp8_f32(a, b, 0, false);
    return (unsigned short)(v & 0xffff);
}
#else
__device__ __forceinline__ unsigned fp8_enc1(float x) {
    float ax = fabsf(x);
    ax = fminf(ax, 448.f);
    unsigned sgn = (__float_as_uint(x) >> 24) & 0x80u;
    float sc = ax * 0x1p-120f;
    unsigned b = __float_as_uint(sc);
    if (b < 0x00080000u) return sgn;
    unsigned r = b + 0x7ffffu + ((b >> 20) & 1u);
    return sgn | (r >> 20);
}
__device__ __forceinline__ unsigned short packfp8_2(float a, float b) {
    return (unsigned short)(fp8_enc1(a) | (fp8_enc1(b) << 8));
}
#endif

// ---------------- degree (per-direction, over src) + dst histogram ----------------
__global__ void deg_hist_kernel(const int* __restrict__ ei, float* deg_in, float* deg_out,
                                int* __restrict__ cnt_dst) {
    int e = blockIdx.x * 256 + threadIdx.x;
    if (e >= N_EDGES) return;
    int src = ei[e];
    int dst = ei[N_EDGES + e];
    if (e < HALF_E) atomicAdd(deg_in + src, 1.0f);
    else            atomicAdd(deg_out + src, 1.0f);
    atomicAdd(cnt_dst + dst, 1);
}

// ---------------- scan phase 1 (+ fused dinv) ----------------
__global__ __launch_bounds__(1024) void scan1_kernel(const int* __restrict__ cnt,
                                                     int* __restrict__ excl,
                                                     int* __restrict__ bsum,
                                                     float* deg_in, float* deg_out) {
    __shared__ int ps[1024];
    int t = threadIdx.x;
    int i = blockIdx.x * 1024 + t;
    if (i < N_NODES) {
        float d = deg_in[i];  deg_in[i]  = d > 0.f ? rsqrtf(d) : 0.f;
        d = deg_out[i];       deg_out[i] = d > 0.f ? rsqrtf(d) : 0.f;
    }
    int v = (i < N_NODES) ? cnt[i] : 0;
    ps[t] = v;
    __syncthreads();
    for (int off = 1; off < 1024; off <<= 1) {
        int u = (t >= off) ? ps[t - off] : 0;
        __syncthreads();
        ps[t] += u;
        __syncthreads();
    }
    if (i < N_NODES) excl[i] = ps[t] - v;
    if (t == 1023) bsum[blockIdx.x] = ps[t];
}

// ---------------- scan phase 2 (+ fused per-graph counts) ----------------
__global__ __launch_bounds__(128) void scan2_kernel(const int* __restrict__ bsum,
                                                    int* __restrict__ boff,
                                                    int* __restrict__ rowptr,
                                                    const int* __restrict__ batch,
                                                    float* __restrict__ cnt_g) {
    __shared__ int ps[128];
    int t = threadIdx.x;
    for (int g = t; g < NG; g += 128) {
        int lo = 0, hi = N_NODES;
        while (lo < hi) { int mid = (lo + hi) >> 1; if (batch[mid] < g) lo = mid + 1; else hi = mid; }
        int start = lo;
        lo = 0; hi = N_NODES;
        while (lo < hi) { int mid = (lo + hi) >> 1; if (batch[mid] < g + 1) lo = mid + 1; else hi = mid; }
        cnt_g[g] = (float)(lo - start);
    }
    int v = (t < SCAN_NB) ? bsum[t] : 0;
    ps[t] = v;
    __syncthreads();
    for (int off = 1; off < 128; off <<= 1) {
        int u = (t >= off) ? ps[t - off] : 0;
        __syncthreads();
        ps[t] += u;
        __syncthreads();
    }
    if (t < SCAN_NB) boff[t] = ps[t] - v;
    if (t == 127) rowptr[N_NODES] = ps[t];
}

__global__ __launch_bounds__(1024) void scan3_kernel(const int* __restrict__ excl,
                                                     const int* __restrict__ boff,
                                                     int* __restrict__ rowptr,
                                                     int* __restrict__ rfill) {
    int t = threadIdx.x;
    int i = blockIdx.x * 1024 + t;
    if (i >= N_NODES) return;
    int r = excl[i] + boff[blockIdx.x];
    rowptr[i] = r;
    rfill[i] = r;
}

// ---------------- fill CSR: mn = { src | (t << 17) | (dir << 25), bits(norm) } ----------------
__global__ void fill_kernel(const int* __restrict__ ei, const int* __restrict__ etype,
                            const float* __restrict__ dinv_in, const float* __restrict__ dinv_out,
                            int* __restrict__ rfill, int2* __restrict__ csr_mn) {
    int e = blockIdx.x * 256 + threadIdx.x;
    if (e >= N_EDGES) return;
    int s = ei[e], d = ei[N_EDGES + e];
    int t = etype[e];
    bool isin = (e < HALF_E);
    const float* dv = isin ? dinv_in : dinv_out;
    float nv = dv[s] * dv[d];
    int j = atomicAdd(rfill + d, 1);
    int m = s | (t << 17) | (isin ? 0 : (1 << 25));
    csr_mn[j] = make_int2(m, __float_as_int(nv));
}

// ---------------- x (f32) -> fp8 for the layer-1 gather ----------------
__global__ void xcvt_kernel(const float* __restrict__ x, unsigned short* __restrict__ Xf8) {
    int id = blockIdx.x * 256 + threadIdx.x;
    if (id >= N_NODES * 64) return;
    float2 v = *(const float2*)(x + (size_t)id * 2);
    Xf8[id] = packfp8_2(v.x, v.y);
}

// ---------------- rel chain: relb_l = bf16(r_l); rbuf <- r_l @ w_rel; lwl <- loop_rel @ w_loop ----------------
__global__ void rel_mm_kernel(const float* __restrict__ rge, const float* __restrict__ loop_rel,
                              int layer,
                              const float* __restrict__ wRel, const float* __restrict__ wLoop,
                              unsigned* __restrict__ relb, float* __restrict__ rbuf,
                              float* __restrict__ lwl) {
    __shared__ float a[H];
    int i = blockIdx.x, j = threadIdx.x;
    float v;
    if (i == 200)        v = loop_rel[j];
    else if (layer == 1) v = (i < 100) ? rge[i * H + j] : -rge[(i - 100) * H + j];
    else                 v = rbuf[i * H + j];
    a[j] = v;
    __syncthreads();
    float vn = __shfl_xor(v, 1);
    if (i < 200 && (j & 1) == 0)
        relb[i * 64 + (j >> 1)] = packbf2(v, vn);
    float s_rel = 0.f, s_loop = 0.f;
    for (int k = 0; k < H; k++) {
        float av = a[k];
        s_rel  += av * wRel [k * H + j];
        s_loop += av * wLoop[k * H + j];
    }
    if (i < 200)  rbuf[i * H + j] = s_rel;
    if (i == 200) lwl[j] = s_loop;
}

// ---------------- weight pre-pack into MFMA B-fragment order (bf16) ----------------
struct WPtrs { const float* p[9]; };
__global__ __launch_bounds__(256) void wpack_kernel(WPtrs wp, unsigned short* __restrict__ Bp) {
    int iw = blockIdx.y;  // l*3 + w   (w: 0=in, 1=out, 2=loop)
    const float* W = wp.p[iw];
    unsigned short* out = Bp + (size_t)iw * 16384;
    int t = blockIdx.x * 256 + threadIdx.x;   // 0..2047
    int nt = t >> 8, kk = (t >> 6) & 3, lane = t & 63;
    int n = nt * 16 + (lane & 15);
    int k0 = kk * 32 + (lane >> 4) * 8;
    unsigned p[4];
    for (int j = 0; j < 4; j++)
        p[j] = packbf2(W[(k0 + 2 * j) * H + n], W[(k0 + 2 * j + 1) * H + n]);
    *(uint4*)(out + ((size_t)(nt * 4 + kk) * 64 + lane) * 8) = make_uint4(p[0], p[1], p[2], p[3]);
}

// ---------------- gather: agg_dir[v] = sum_edges (x[src] - rel[t]) * norm  (per direction) ----------------
__global__ __launch_bounds__(256, 8) void gather_kernel(const int* __restrict__ rowptr,
                                                        const int2* __restrict__ csr_mn,
                                                        const unsigned short* __restrict__ Xf8,
                                                        const unsigned* __restrict__ RELb,
                                                        unsigned* __restrict__ AGGi,
                                                        unsigned* __restrict__ AGGo) {
    int v = blockIdx.x * 4 + (threadIdx.x >> 6);
    if (v >= N_NODES) return;
    int lane = threadIdx.x & 63;
    int jb = rowptr[v], je = rowptr[v + 1];
    float aix = 0.f, aiy = 0.f, aox = 0.f, aoy = 0.f;
    int j = jb;
    for (; j + 7 < je; j += 8) {
        int2 mn[8];
        #pragma unroll
        for (int k = 0; k < 8; k++) mn[k] = csr_mn[j + k];
        unsigned short xq[8]; unsigned rl[8];
        #pragma unroll
        for (int k = 0; k < 8; k++) {
            xq[k] = Xf8[(size_t)(mn[k].x & 0x1FFFF) * 64 + lane];
            rl[k] = RELb[((mn[k].x >> 17) & 0xFF) * 64 + lane];
        }
        #pragma unroll
        for (int k = 0; k < 8; k++) {
            float n = __int_as_float(mn[k].y);
            f32x2 dx = f8pair(xq[k]);
            float vx = dx.x - bflo(rl[k]);
            float vy = dx.y - bfhi(rl[k]);
            bool dir = (mn[k].x >> 25) & 1;
            float ni = dir ? 0.f : n, no = dir ? n : 0.f;
            aix += vx * ni; aiy += vy * ni;
            aox += vx * no; aoy += vy * no;
        }
    }
    for (; j < je; j++) {
        int2 mn0 = csr_mn[j];
        float n = __int_as_float(mn0.y);
        unsigned short xq = Xf8[(size_t)(mn0.x & 0x1FFFF) * 64 + lane];
        unsigned rl = RELb[((mn0.x >> 17) & 0xFF) * 64 + lane];
        f32x2 dx = f8pair(xq);
        float vx = dx.x - bflo(rl);
        float vy = dx.y - bfhi(rl);
        bool dir = (mn0.x >> 25) & 1;
        float ni = dir ? 0.f : n, no = dir ? n : 0.f;
        aix += vx * ni; aiy += vy * ni;
        aox += vx * no; aoy += vy * no;
    }
    AGGi[(size_t)v * 64 + lane] = packbf2(aix, aiy);
    AGGo[(size_t)v * 64 + lane] = packbf2(aox, aoy);
}

// ---------------- combine (MFMA): new_x = act( (AGGi@w_in + AGGo@w_out + x@w_loop - lwl)/3 + b ) ----------------
__global__ __launch_bounds__(256) void combine_kernel(const float* __restrict__ Xf,
                                                      const unsigned* __restrict__ Xh,
                                                      int xf32,
                                                      const unsigned* __restrict__ AGGi,
                                                      const unsigned* __restrict__ AGGo,
                                                      const unsigned short* __restrict__ Bpack,
                                                      const float* __restrict__ lwl,
                                                      const float* __restrict__ bvec,
                                                      unsigned short* __restrict__ Xf8_out,
                                                      unsigned* __restrict__ Xh_out,
                                                      const int* __restrict__ batch,
                                                      float* __restrict__ pool, int mode) {
    __shared__ unsigned short ti[MMB * XPITCH];   // agg_in tile; reused as fp8 staging
    __shared__ unsigned short to[MMB * XPITCH];   // agg_out tile; reused as bf16 staging
    __shared__ unsigned short tx[MMB * XPITCH];   // x tile
    int tid = threadIdx.x;
    int row0 = blockIdx.x * MMB;
    int nrows = min(MMB, N_NODES - row0);

    // stage agg_in / agg_out (bf16 rows = 16 uint4)
    for (int t = 0; t < 4; t++) {
        int idx = tid + t * 256;                 // 1024 uint4 slots
        int r = idx >> 4, c8 = (idx & 15) * 8;   // 8 ushorts per uint4
        if (r < nrows) {
            *(uint4*)(ti + r * XPITCH + c8) = *(const uint4*)((const unsigned short*)AGGi + (size_t)(row0 + r) * H + c8);
            *(uint4*)(to + r * XPITCH + c8) = *(const uint4*)((const unsigned short*)AGGo + (size_t)(row0 + r) * H + c8);
        }
    }
    // stage x
    if (xf32) {
        for (int t = 0; t < 8; t++) {
            int idx = tid + t * 256;
            int r = idx >> 5, c4 = (idx & 31) * 4;
            if (r < nrows) {
                float4 v = *(const float4*)(Xf + (size_t)(row0 + r) * H + c4);
                *(uint2*)(tx + r * XPITCH + c4) = make_uint2(packbf2(v.x, v.y), packbf2(v.z, v.w));
            }
        }
    } else {
        for (int t = 0; t < 4; t++) {
            int idx = tid + t * 256;
            int r = idx >> 4, c8 = (idx & 15) * 8;
            if (r < nrows)
                *(uint4*)(tx + r * XPITCH + c8) = *(const uint4*)((const unsigned short*)Xh + (size_t)(row0 + r) * H + c8);
        }
    }
    __syncthreads();

    int wave = tid >> 6, lane = tid & 63;
    int m0w = wave * 16;
    int q = lane >> 4, ml = lane & 15;
    bf16x8 fi[4], fo[4], fx[4];
    for (int kk = 0; kk < 4; kk++) {
        fi[kk] = *(const bf16x8*)(ti + (m0w + ml) * XPITCH + kk * 32 + q * 8);
        fo[kk] = *(const bf16x8*)(to + (m0w + ml) * XPITCH + kk * 32 + q * 8);
        fx[kk] = *(const bf16x8*)(tx + (m0w + ml) * XPITCH + kk * 32 + q * 8);
    }
    __syncthreads();   // ti/to free for staging reuse

    if (m0w + 16 > nrows) return;   // whole 16-row group (N % 16 == 0)

    int grow0 = row0 + m0w;
    int grow_base = grow0 + q * 4;
    unsigned short* stg8 = ti + wave * 1024;            // 16 rows x 64 ushorts (fp8)
    unsigned* stgh = (unsigned*)to + wave * 1024;       // 16 rows x 64 uints (bf16)

    int gmap[4];
    if (mode == 1) {
        #pragma unroll
        for (int reg = 0; reg < 4; reg++) gmap[reg] = batch[grow_base + reg];
    }

    for (int nt = 0; nt < 8; nt++) {
        f32x4 acc = {0.f, 0.f, 0.f, 0.f};
        const unsigned short* bpI = Bpack + (((size_t)(0 * 8 + nt) * 4) * 64 + lane) * 8;
        const unsigned short* bpO = Bpack + (((size_t)(1 * 8 + nt) * 4) * 64 + lane) * 8;
        const unsigned short* bpL = Bpack + (((size_t)(2 * 8 + nt) * 4) * 64 + lane) * 8;
        for (int kk = 0; kk < 4; kk++)
            acc = __builtin_amdgcn_mfma_f32_16x16x32_bf16(fi[kk], *(const bf16x8*)(bpI + (size_t)kk * 512), acc, 0, 0, 0);
        for (int kk = 0; kk < 4; kk++)
            acc = __builtin_amdgcn_mfma_f32_16x16x32_bf16(fo[kk], *(const bf16x8*)(bpO + (size_t)kk * 512), acc, 0, 0, 0);
        for (int kk = 0; kk < 4; kk++)
            acc = __builtin_amdgcn_mfma_f32_16x16x32_bf16(fx[kk], *(const bf16x8*)(bpL + (size_t)kk * 512), acc, 0, 0, 0);
        int col = nt * 16 + ml;
        float sub = lwl[col];
        float bb = bvec[col];
        if (mode == 0) {
            #pragma unroll
            for (int reg = 0; reg < 4; reg++) {
                float val = fmaxf(tanhf((acc[reg] - sub) * (1.f / 3.f) + bb), 0.f);
                float vn = __shfl_xor(val, 1);
                if ((lane & 1) == 0) {
                    stg8[(q * 4 + reg) * 64 + nt * 8 + (ml >> 1)] = packfp8_2(val, vn);
                    stgh[(q * 4 + reg) * 64 + nt * 8 + (ml >> 1)] = packbf2(val, vn);
                }
            }
        } else {
            #pragma unroll
            for (int reg = 0; reg < 4; reg++) {
                float val = tanhf((acc[reg] - sub) * (1.f / 3.f) + bb);
                atomicAdd(pool + gmap[reg] * H + col, val);
            }
        }
    }
    if (mode == 0) {
        // coalesced stores: fp8 = 16 rows x 8 uint4; bf16 = 16 rows x 16 uint4
        uint4* s8 = (uint4*)stg8;
        uint4* d8 = (uint4*)Xf8_out + (size_t)grow0 * 8;
        d8[lane]      = s8[lane];
        d8[lane + 64] = s8[lane + 64];
        uint4* sh = (uint4*)stgh;
        uint4* dh = (uint4*)Xh_out + (size_t)grow0 * 16;
        #pragma unroll
        for (int i = 0; i < 4; i++)
            dh[lane + 64 * i] = sh[lane + 64 * i];
    }
}

// ---------------- final: out[g] = [mean, rel_emb] @ lin_w + lin_b ----------------
__global__ void final_kernel(const float* __restrict__ pool, const float* __restrict__ cnt,
                             const float* __restrict__ rel_table, const int* __restrict__ rel_labels,
                             const float* __restrict__ lin_w, const float* __restrict__ lin_b,
                             float* __restrict__ out) {
    int g = blockIdx.x;
    int lane = threadIdx.x;   // 64
    float inv = 1.f / fmaxf(cnt[g], 1.f);
    const float* rrow = rel_table + (size_t)rel_labels[g] * H;
    float p0 = 0.f, p1 = 0.f;
    for (int c = lane; c < H; c += 64) {
        float m = pool[g * H + c] * inv;
        p0 += m * lin_w[c * 2 + 0];
        p1 += m * lin_w[c * 2 + 1];
        float rv = rrow[c];
        p0 += rv * lin_w[(H + c) * 2 + 0];
        p1 += rv * lin_w[(H + c) * 2 + 1];
    }
    for (int off = 32; off; off >>= 1) {
        p0 += __shfl_down(p0, off);
        p1 += __shfl_down(p1, off);
    }
    if (lane == 0) {
        out[g * 2 + 0] = p0 + lin_b[0];
        out[g * 2 + 1] = p1 + lin_b[1];
    }
}

extern "C" void kernel_launch(void* const* d_in, const int* in_sizes, int n_in,
                              void* d_out, int out_size, void* d_ws, size_t ws_size,
                              hipStream_t stream) {
    const float* x          = (const float*)d_in[0];
    const int*   ei         = (const int*)  d_in[1];
    const int*   etype      = (const int*)  d_in[2];
    const int*   batch      = (const int*)  d_in[3];
    const int*   rel_labels = (const int*)  d_in[4];
    const float* rel_table  = (const float*)d_in[6];
    const float* rge        = (const float*)d_in[7];
    const float* lin_w      = (const float*)d_in[26];
    const float* lin_b      = (const float*)d_in[27];
    float* out = (float*)d_out;

    // ---- workspace layout (big aligned arrays first) ----
    int2*  csr_mn = (int2*)d_ws;                                   // E int2
    unsigned short* Xf8 = (unsigned short*)(csr_mn + N_EDGES);     // N*64 ushorts (fp8 pairs)
    unsigned* Xh   = (unsigned*)(Xf8 + (size_t)N_NODES * 64);      // N*64 uints (bf16 pairs)
    unsigned* AGGi = Xh + (size_t)N_NODES * 64;                    // N*64 uints
    unsigned* AGGo = AGGi + (size_t)N_NODES * 64;                  // N*64 uints
    unsigned* relb = AGGo + (size_t)N_NODES * 64;                  // 3*200*64 uints
    unsigned short* Bpack = (unsigned short*)(relb + 3 * 200 * 64);// 9*16384 ushorts
    float* dinv_in  = (float*)(Bpack + 9 * 16384);                 // N
    float* dinv_out = dinv_in + N_NODES;                           // N
    float* pool     = dinv_out + N_NODES;                          // NG*H
    float* cnt      = pool + NG * H;                               // NG
    float* rbuf     = cnt + NG;                                    // 200*H
    float* lwl      = rbuf + 200 * H;                              // 3*H
    int*   rowptr   = (int*)(lwl + 3 * H);                         // N+4
    int*   rfill    = rowptr + N_NODES + 4;                        // N
    int*   cnt_dst  = rfill + N_NODES;                             // N
    int*   excl     = cnt_dst + N_NODES;                           // N
    int*   bsum     = excl + N_NODES;                              // 100
    int*   boff     = bsum + 100;                                  // 100

    hipMemsetAsync(dinv_in, 0, (size_t)(2 * N_NODES + NG * H + NG) * sizeof(float), stream);
    hipMemsetAsync(cnt_dst, 0, (size_t)N_NODES * sizeof(int), stream);

    deg_hist_kernel<<<(N_EDGES + 255) / 256, 256, 0, stream>>>(ei, dinv_in, dinv_out, cnt_dst);
    scan1_kernel   <<<SCAN_NB, 1024, 0, stream>>>(cnt_dst, excl, bsum, dinv_in, dinv_out);
    scan2_kernel   <<<1, 128, 0, stream>>>(bsum, boff, rowptr, batch, cnt);
    scan3_kernel   <<<SCAN_NB, 1024, 0, stream>>>(excl, boff, rowptr, rfill);
    fill_kernel    <<<(N_EDGES + 255) / 256, 256, 0, stream>>>(ei, etype, dinv_in, dinv_out,
                                                               rfill, csr_mn);
    xcvt_kernel    <<<(N_NODES * 64 + 255) / 256, 256, 0, stream>>>(x, Xf8);

    WPtrs wp;
    for (int l = 0; l < 3; l++) {
        wp.p[l * 3 + 0] = (const float*)d_in[8 + 6 * l + 0];  // wIn
        wp.p[l * 3 + 1] = (const float*)d_in[8 + 6 * l + 1];  // wOut
        wp.p[l * 3 + 2] = (const float*)d_in[8 + 6 * l + 2];  // wLoop
    }
    wpack_kernel<<<dim3(8, 9), 256, 0, stream>>>(wp, Bpack);

    // rel chain up-front: relb_l (bf16 raw rel), rbuf -> next rel, lwl_l
    for (int l = 0; l < 3; l++) {
        const float* wRel  = (const float*)d_in[8 + 6 * l + 3];
        const float* wLoop = (const float*)d_in[8 + 6 * l + 2];
        const float* lrel  = (const float*)d_in[8 + 6 * l + 4];
        rel_mm_kernel<<<RELROWS, H, 0, stream>>>(rge, lrel, l + 1, wRel, wLoop,
                                                 relb + (size_t)l * 200 * 64,
                                                 rbuf, lwl + l * H);
    }

    // three conv layers: gather (on raw x, fp8) then combine (3-way MFMA + activation)
    int cmb_grid = (N_NODES + MMB - 1) / MMB;
    for (int l = 0; l < 3; l++) {
        const float* bl = (const float*)d_in[8 + 6 * l + 5];
        gather_kernel<<<N_NODES / 4, 256, 0, stream>>>(rowptr, csr_mn, Xf8,
                                                       relb + (size_t)l * 200 * 64,
                                                       AGGi, AGGo);
        combine_kernel<<<cmb_grid, 256, 0, stream>>>(x, Xh, (l == 0) ? 1 : 0,
                                                     AGGi, AGGo,
                                                     Bpack + (size_t)l * 3 * 16384,
                                                     lwl + l * H, bl,
                                                     Xf8, Xh, batch, pool, (l == 2) ? 1 : 0);
    }

    final_kernel<<<NG, 64, 0, stream>>>(pool, cnt, rel_table, rel_labels, lin_w, lin_b, out);
}